// Round 1
// baseline (698.960 us; speedup 1.0000x reference)
//
#include <hip/hip_runtime.h>
#include <hip/hip_bf16.h>

#define DIM 2048
#define SEQLEN 2048
#define NHEADS 16
#define HDIM 128
#define NBATCH 2

using short8 = __attribute__((ext_vector_type(8))) short;
using f32x4 = __attribute__((ext_vector_type(4))) float;
using ushort4v = __attribute__((ext_vector_type(4))) unsigned short;

typedef __attribute__((address_space(1))) const void gvoid_t;
typedef __attribute__((address_space(3))) void lvoid_t;

__device__ __forceinline__ void gl_lds16(const void* g, void* l) {
  __builtin_amdgcn_global_load_lds((gvoid_t*)g, (lvoid_t*)l, 16, 0, 0);
}

__device__ __forceinline__ unsigned short f2bf(float f) {
  union { float f; unsigned int u; } v;
  v.f = f;
  unsigned int u = v.u;
  return (unsigned short)((u + 0x7FFFu + ((u >> 16) & 1u)) >> 16);
}

__device__ __forceinline__ f32x4 mfma16(short8 a, short8 b, f32x4 c) {
  return __builtin_amdgcn_mfma_f32_16x16x32_bf16(a, b, c, 0, 0, 0);
}

// ---------------------------------------------------------------- cast fp32->bf16
__global__ __launch_bounds__(256) void cast_all(
    const float4* __restrict__ x,
    const float4* __restrict__ wq, const float4* __restrict__ wk,
    const float4* __restrict__ wv, const float4* __restrict__ wo,
    ushort4v* __restrict__ xb,
    ushort4v* __restrict__ wqb, ushort4v* __restrict__ wkb,
    ushort4v* __restrict__ wvb, ushort4v* __restrict__ wob)
{
  const long NXV = 2097152;   // 8388608/4
  const long NWV = 1048576;   // 4194304/4
  long tid = (long)blockIdx.x * blockDim.x + threadIdx.x;
  long nth = (long)gridDim.x * blockDim.x;
  for (long i = tid; i < NXV + 4 * NWV; i += nth) {
    const float4* s; ushort4v* dst; long off;
    if (i < NXV) { s = x; dst = xb; off = i; }
    else {
      long j = i - NXV;
      int w = (int)(j >> 20);
      off = j & (NWV - 1);
      switch (w) {
        case 0:  s = wq; dst = wqb; break;
        case 1:  s = wk; dst = wkb; break;
        case 2:  s = wv; dst = wvb; break;
        default: s = wo; dst = wob; break;
      }
    }
    float4 f = s[off];
    ushort4v u;
    u.x = f2bf(f.x); u.y = f2bf(f.y); u.z = f2bf(f.z); u.w = f2bf(f.w);
    dst[off] = u;
  }
}

// ---------------------------------------------------------------- rope cos/sin tables [S][64]
__global__ __launch_bounds__(256) void rope_tables(float* __restrict__ ctab,
                                                   float* __restrict__ stab)
{
  int idx = blockIdx.x * 256 + threadIdx.x;
  if (idx >= SEQLEN * 64) return;
  int s = idx >> 6, i = idx & 63;
  float inv = powf(10000.0f, -(float)(2 * i) * (1.0f / 128.0f));
  float a = (float)s * inv;
  ctab[idx] = cosf(a);
  stab[idx] = sinf(a);
}

// ---------------------------------------------------------------- GEMM C = A*B^T (A:MxK, B:NxK, bf16)
// m97 structure: 128x128 tile, BK=32, global_load_lds(16B), 16x16x32 bf16 MFMA.
template<bool ROPE, bool WF32, bool WBF16>
__global__ __launch_bounds__(256) void gemm_bt(
    const unsigned short* __restrict__ A,
    const unsigned short* __restrict__ B,
    float* __restrict__ Cf,
    unsigned short* __restrict__ Cb,
    int M, int N, int K,
    const float* __restrict__ ctab,
    const float* __restrict__ stab,
    float premul)
{
  __shared__ unsigned short As[128 * 32];
  __shared__ unsigned short Bs[128 * 32];
  const int tid = threadIdx.x;
  const int wv = tid >> 6;
  const int lane = tid & 63;
  const int q4 = lane >> 4;
  const int l15 = lane & 15;
  const int m0 = blockIdx.y * 128;
  const int n0 = blockIdx.x * 128;
  const int wy = wv >> 1, wx = wv & 1;   // 2x2 waves, 64x64 each

  f32x4 acc[4][4];
  for (int i = 0; i < 4; ++i)
    for (int j = 0; j < 4; ++j)
      acc[i][j] = f32x4{0.f, 0.f, 0.f, 0.f};

  for (int k0 = 0; k0 < K; k0 += 32) {
    // stage A,B tiles (row-major [128][32], 16B chunks; slot = row*4+chunk)
    for (int j = 0; j < 2; ++j) {
      int sb = wv * 128 + j * 64;
      int slot = sb + lane;
      int r = slot >> 2, c = slot & 3;
      gl_lds16(A + (size_t)(m0 + r) * K + k0 + c * 8, &As[sb * 8]);
      gl_lds16(B + (size_t)(n0 + r) * K + k0 + c * 8, &Bs[sb * 8]);
    }
    __syncthreads();
    short8 af[4], bf[4];
    for (int i = 0; i < 4; ++i) {
      int row = wy * 64 + i * 16 + l15;
      af[i] = *reinterpret_cast<const short8*>(&As[row * 32 + q4 * 8]);
    }
    for (int j = 0; j < 4; ++j) {
      int col = wx * 64 + j * 16 + l15;
      bf[j] = *reinterpret_cast<const short8*>(&Bs[col * 32 + q4 * 8]);
    }
    for (int i = 0; i < 4; ++i)
      for (int j = 0; j < 4; ++j)
        acc[i][j] = mfma16(af[i], bf[j], acc[i][j]);
    __syncthreads();
  }

  // epilogue: C/D layout col=lane&15, row=(lane>>4)*4+reg (m89-verified)
  for (int i = 0; i < 4; ++i) {
    for (int j = 0; j < 4; ++j) {
      int colb = n0 + wx * 64 + j * 16 + l15;
      for (int r = 0; r < 4; ++r) {
        int row = m0 + wy * 64 + i * 16 + q4 * 4 + r;
        float val = acc[i][j][r];
        if (ROPE) {
          int s = row & (SEQLEN - 1);
          int pi = (colb & (HDIM - 1)) >> 1;
          float cs = ctab[(s << 6) + pi];
          float sn = stab[(s << 6) + pi];
          float partner = __shfl_xor(val, 1);  // adjacent head-dim column = adjacent lane
          val = (colb & 1) ? fmaf(partner, sn, val * cs)
                           : fmaf(val, cs, -partner * sn);
        }
        if (WF32) Cf[(size_t)row * N + colb] = val;
        if (WBF16) Cb[(size_t)row * N + colb] = f2bf(val * premul);
      }
    }
  }
}

// ---------------------------------------------------------------- V (B,S,D) f32 -> Vt (B*H,128,S) bf16
__global__ __launch_bounds__(256) void transpose_v(const float* __restrict__ v,
                                                   unsigned short* __restrict__ vt)
{
  __shared__ float tile[64][65];
  const int b = blockIdx.z;
  const int s0 = blockIdx.y * 64;
  const int d0 = blockIdx.x * 64;
  const int tx = threadIdx.x & 63;
  const int ty = threadIdx.x >> 6;
  for (int r = 0; r < 16; ++r) {
    int srow = r * 4 + ty;
    tile[srow][tx] = v[((size_t)(b * SEQLEN + s0 + srow)) * DIM + d0 + tx];
  }
  __syncthreads();
  for (int r = 0; r < 16; ++r) {
    int drow = r * 4 + ty;
    int d = d0 + drow;
    int bh = b * NHEADS + (d >> 7);
    int dh = d & 127;
    vt[((size_t)(bh * HDIM + dh)) * SEQLEN + s0 + tx] = f2bf(tile[tx][drow]);
  }
}

// ---------------------------------------------------------------- flash attention
// Q-tile 128 rows, KV-tile 128. KP buffer holds Q-staging, then K, then P.
// LDS chunk swizzle c' = c ^ (row&7): keeps global_load_lds contiguous, makes
// ds_read_b128 2-way (free) instead of 16-way conflicted.
__global__ __launch_bounds__(256, 2) void flash_attn(
    const unsigned short* __restrict__ qb,
    const unsigned short* __restrict__ kb,
    const unsigned short* __restrict__ vt,
    unsigned short* __restrict__ ab)
{
  __shared__ unsigned short KP[128 * 128];
  __shared__ unsigned short VTs[128 * 128];
  const int tid = threadIdx.x;
  const int wv = tid >> 6;
  const int lane = tid & 63;
  const int q4 = lane >> 4;
  const int l15 = lane & 15;
  const int q0 = blockIdx.x * 128;
  const int bh = blockIdx.y;
  const int b = bh >> 4, h = bh & 15;

  const unsigned short* qbase = qb + (size_t)b * SEQLEN * DIM + h * HDIM;
  const unsigned short* kbase = kb + (size_t)b * SEQLEN * DIM + h * HDIM;
  const unsigned short* vbase = vt + (size_t)bh * HDIM * SEQLEN;

  // stage Q tile (128x128) into KP, swizzled
  for (int j = 0; j < 8; ++j) {
    int sb = (wv * 8 + j) * 64;
    int slot = sb + lane;
    int row = slot >> 4, cp = slot & 15;
    int c = cp ^ (row & 7);
    gl_lds16(qbase + (size_t)(q0 + row) * DIM + c * 8, &KP[sb * 8]);
  }
  __syncthreads();
  short8 qf[2][4];
  for (int rt = 0; rt < 2; ++rt) {
    int row = wv * 32 + rt * 16 + l15;
    for (int ks = 0; ks < 4; ++ks) {
      int c = (ks * 4 + q4) ^ (row & 7);
      qf[rt][ks] = *reinterpret_cast<const short8*>(&KP[row * 128 + c * 8]);
    }
  }
  __syncthreads();

  float m_run[2][4], l_run[2][4];
  f32x4 o[2][8];
  for (int rt = 0; rt < 2; ++rt)
    for (int r = 0; r < 4; ++r) { m_run[rt][r] = -3.0e38f; l_run[rt][r] = 0.f; }
  for (int rt = 0; rt < 2; ++rt)
    for (int ct = 0; ct < 8; ++ct)
      o[rt][ct] = f32x4{0.f, 0.f, 0.f, 0.f};

  for (int kv = 0; kv < SEQLEN / 128; ++kv) {
    const int kv0 = kv * 128;
    for (int j = 0; j < 8; ++j) {
      int sb = (wv * 8 + j) * 64;
      int slot = sb + lane;
      int row = slot >> 4, cp = slot & 15;
      int c = cp ^ (row & 7);
      gl_lds16(kbase + (size_t)(kv0 + row) * DIM + c * 8, &KP[sb * 8]);
      gl_lds16(vbase + (size_t)row * SEQLEN + kv0 + c * 8, &VTs[sb * 8]);
    }
    __syncthreads();

    // scores: S[q][key], A=Q (regs), B=K (LDS). Q was pre-scaled by Dh^-0.5.
    f32x4 sc[2][8];
    for (int rt = 0; rt < 2; ++rt)
      for (int ct = 0; ct < 8; ++ct)
        sc[rt][ct] = f32x4{0.f, 0.f, 0.f, 0.f};
    for (int ct = 0; ct < 8; ++ct) {
      int krow = ct * 16 + l15;
      for (int ks = 0; ks < 4; ++ks) {
        int c = (ks * 4 + q4) ^ (krow & 7);
        short8 kf = *reinterpret_cast<const short8*>(&KP[krow * 128 + c * 8]);
        sc[0][ct] = mfma16(qf[0][ks], kf, sc[0][ct]);
        sc[1][ct] = mfma16(qf[1][ks], kf, sc[1][ct]);
      }
    }

    // online softmax (row = (lane>>4)*4 + reg; row-reduce = shfl over 16 lanes)
    float al[2][4];
    for (int rt = 0; rt < 2; ++rt) {
      for (int r = 0; r < 4; ++r) {
        float mx = sc[rt][0][r];
        for (int ct = 1; ct < 8; ++ct) mx = fmaxf(mx, sc[rt][ct][r]);
        for (int d = 1; d < 16; d <<= 1) mx = fmaxf(mx, __shfl_xor(mx, d));
        float mnew = fmaxf(m_run[rt][r], mx);
        al[rt][r] = __expf(m_run[rt][r] - mnew);
        m_run[rt][r] = mnew;
      }
      float rs[4] = {0.f, 0.f, 0.f, 0.f};
      for (int ct = 0; ct < 8; ++ct) {
        f32x4 p;
        for (int r = 0; r < 4; ++r) {
          float e = __expf(sc[rt][ct][r] - m_run[rt][r]);
          p[r] = e;
          rs[r] += e;
        }
        sc[rt][ct] = p;
      }
      for (int r = 0; r < 4; ++r) {
        float t = rs[r];
        for (int d = 1; d < 16; d <<= 1) t += __shfl_xor(t, d);
        l_run[rt][r] = l_run[rt][r] * al[rt][r] + t;
      }
      for (int ct = 0; ct < 8; ++ct)
        for (int r = 0; r < 4; ++r)
          o[rt][ct][r] *= al[rt][r];
    }

    __syncthreads();  // all waves done reading K before P overwrites KP

    // write P (bf16) into KP, C-layout -> swizzled rows; each wave touches only
    // its own 32 rows, so no extra barrier before its own A-frag reads.
    for (int rt = 0; rt < 2; ++rt) {
      for (int ct = 0; ct < 8; ++ct) {
        int col = ct * 16 + l15;
        for (int r = 0; r < 4; ++r) {
          int prow = wv * 32 + rt * 16 + q4 * 4 + r;
          int cp = (col >> 3) ^ (prow & 7);
          KP[prow * 128 + cp * 8 + (col & 7)] = f2bf(sc[rt][ct][r]);
        }
      }
    }
    __asm__ volatile("s_waitcnt lgkmcnt(0)" ::: "memory");

    short8 pf[2][4];
    for (int rt = 0; rt < 2; ++rt) {
      int prow = wv * 32 + rt * 16 + l15;
      for (int ks = 0; ks < 4; ++ks) {
        int c = (ks * 4 + q4) ^ (prow & 7);
        pf[rt][ks] = *reinterpret_cast<const short8*>(&KP[prow * 128 + c * 8]);
      }
    }
    // PV: O[q][dh] += P[q][key] * Vt[dh][key]
    for (int ct = 0; ct < 8; ++ct) {
      int vrow = ct * 16 + l15;
      for (int ks = 0; ks < 4; ++ks) {
        int c = (ks * 4 + q4) ^ (vrow & 7);
        short8 vf = *reinterpret_cast<const short8*>(&VTs[vrow * 128 + c * 8]);
        o[0][ct] = mfma16(pf[0][ks], vf, o[0][ct]);
        o[1][ct] = mfma16(pf[1][ks], vf, o[1][ct]);
      }
    }
    __syncthreads();  // before next tile staging overwrites KP/VTs
  }

  for (int rt = 0; rt < 2; ++rt) {
    for (int r = 0; r < 4; ++r) {
      float invl = 1.0f / l_run[rt][r];
      int qrow = q0 + wv * 32 + rt * 16 + q4 * 4 + r;
      size_t base = ((size_t)(b * SEQLEN + qrow)) * DIM + h * HDIM;
      for (int ct = 0; ct < 8; ++ct) {
        ab[base + ct * 16 + l15] = f2bf(o[rt][ct][r] * invl);
      }
    }
  }
}

// ---------------------------------------------------------------- launch
extern "C" void kernel_launch(void* const* d_in, const int* in_sizes, int n_in,
                              void* d_out, int out_size, void* d_ws, size_t ws_size,
                              hipStream_t stream) {
  const float* x  = (const float*)d_in[0];
  const float* wq = (const float*)d_in[1];
  const float* wk = (const float*)d_in[2];
  const float* wv = (const float*)d_in[3];
  const float* wo = (const float*)d_in[4];

  float* outp = (float*)d_out;
  float* kout = outp + 8388608;
  float* vout = outp + 16777216;

  unsigned short* ws  = (unsigned short*)d_ws;
  unsigned short* xb  = ws;                   // 8388608
  unsigned short* wqb = xb + 8388608;         // 4194304 each
  unsigned short* wkb = wqb + 4194304;
  unsigned short* wvb = wkb + 4194304;
  unsigned short* wob = wvb + 4194304;
  unsigned short* qb  = wob + 4194304;        // 8388608 (rope'd, pre-scaled)
  unsigned short* kb  = qb + 8388608;         // 8388608 (rope'd)
  unsigned short* vtb = kb + 8388608;         // 8388608 (V^T per head)
  unsigned short* abuf = vtb + 8388608;       // 8388608 (attention out bf16)
  float* ctab = (float*)(abuf + 8388608);     // 131072 f32
  float* stab = ctab + 131072;                // 131072 f32
  // total ws use: ~113 MB

  cast_all<<<2048, 256, 0, stream>>>(
      (const float4*)x, (const float4*)wq, (const float4*)wk,
      (const float4*)wv, (const float4*)wo,
      (ushort4v*)xb, (ushort4v*)wqb, (ushort4v*)wkb,
      (ushort4v*)wvb, (ushort4v*)wob);
  rope_tables<<<512, 256, 0, stream>>>(ctab, stab);

  dim3 gg(16, 32);  // N/128, M/128
  const float qscale = 0.08838834764831845f;  // 1/sqrt(128)
  gemm_bt<true,  false, true ><<<gg, 256, 0, stream>>>(xb, wqb, nullptr, qb, 4096, 2048, 2048, ctab, stab, qscale);
  gemm_bt<true,  true,  true ><<<gg, 256, 0, stream>>>(xb, wkb, kout,    kb, 4096, 2048, 2048, ctab, stab, 1.0f);
  gemm_bt<false, true,  false><<<gg, 256, 0, stream>>>(xb, wvb, vout, nullptr, 4096, 2048, 2048, ctab, stab, 1.0f);

  transpose_v<<<dim3(32, 32, 2), 256, 0, stream>>>(vout, vtb);
  flash_attn<<<dim3(16, 32), 256, 0, stream>>>(qb, kb, vtb, abuf);

  gemm_bt<false, true,  false><<<gg, 256, 0, stream>>>(abuf, wob, outp, nullptr, 4096, 2048, 2048, ctab, stab, 1.0f);
}